// Round 7
// baseline (479.814 us; speedup 1.0000x reference)
//
#include <hip/hip_runtime.h>
#include <hip/hip_bf16.h>

typedef __attribute__((ext_vector_type(8))) short short8;
typedef __attribute__((ext_vector_type(4))) float f32x4;

static __device__ __forceinline__ f32x4 MFMA16(short8 a, short8 b, f32x4 c) {
    return __builtin_amdgcn_mfma_f32_16x16x32_bf16(a, b, c, 0, 0, 0);
}
static __device__ __forceinline__ unsigned short f2bf(float f) {
    union { __hip_bfloat16 h; unsigned short u; } c;
    c.h = __float2bfloat16(f);
    return c.u;
}
static __device__ __forceinline__ void gload16(const void* g, void* l) {
    __builtin_amdgcn_global_load_lds(
        (const __attribute__((address_space(1))) unsigned int*)g,
        (__attribute__((address_space(3))) unsigned int*)l, 16, 0, 0);
}

// ---------------- ws layout ----------------
// wst  : bf16, LDS-order pre-swizzled w_in  [6 hp][6 s][1536 granules x16B] @ 0        (884736)
// wos  : bf16, LDS-order pre-swizzled w_out [3 nb][6 s][1024 granules x16B] @ 884736   (294912)
// brr  : f32  [12][96] head-major bias                                      @ 1179648  (4608)
// attst: bf16, LDS-order pre-swizzled att   [1024 mb][6 s][16384 B]         @ 1184256  (100663296)
constexpr size_t kWstOff = 0;
constexpr size_t kWosOff = 884736;
constexpr size_t kBrrOff = 1179648;
constexpr size_t kAttOff = 1184256;

// ================= kernel 0: prep (convert + reorder + pre-swizzle weights) =====
__global__ void prep(const float* __restrict__ w_in, const float* __restrict__ b_in,
                     const float* __restrict__ w_out,
                     char* __restrict__ wst, char* __restrict__ wos,
                     float* __restrict__ brr)
{
    const int i = blockIdx.x * 256 + threadIdx.x;   // grid covers 73728 exactly
    if (i < 55296) {
        int hp = i / 9216, rem = i % 9216;
        int s = rem / 1536, slot16 = rem % 1536;
        int row = slot16 >> 3, sl = slot16 & 7;
        int c8 = sl ^ (row & 7);
        int hh = row / 96, rr = row % 96;
        int sec = rr >> 5, d = rr & 31;
        int srow = sec * 384 + (hp * 2 + hh) * 32 + d;
        int k0 = s * 64 + c8 * 8;
        const float4* src = (const float4*)(w_in + (size_t)srow * 384 + k0);
        float4 a = src[0], b = src[1];
        uint4 w;
        w.x = f2bf(a.x) | ((unsigned)f2bf(a.y) << 16);
        w.y = f2bf(a.z) | ((unsigned)f2bf(a.w) << 16);
        w.z = f2bf(b.x) | ((unsigned)f2bf(b.y) << 16);
        w.w = f2bf(b.z) | ((unsigned)f2bf(b.w) << 16);
        *(uint4*)(wst + (size_t)i * 16) = w;
    } else {
        int j = i - 55296;                           // [0, 18432)
        int nb = j / 6144, rem = j % 6144;
        int s = rem / 1024, slot16 = rem % 1024;
        int row = slot16 >> 3, sl = slot16 & 7;
        int c8 = sl ^ (row & 7);
        int srow = nb * 128 + row;
        int k0 = s * 64 + c8 * 8;
        const float4* src = (const float4*)(w_out + (size_t)srow * 384 + k0);
        float4 a = src[0], b = src[1];
        uint4 w;
        w.x = f2bf(a.x) | ((unsigned)f2bf(a.y) << 16);
        w.y = f2bf(a.z) | ((unsigned)f2bf(a.w) << 16);
        w.z = f2bf(b.x) | ((unsigned)f2bf(b.y) << 16);
        w.w = f2bf(b.z) | ((unsigned)f2bf(b.w) << 16);
        *(uint4*)(wos + (size_t)j * 16) = w;
    }
    if (i < 1152) {
        int h = i / 96, jj = i % 96;
        int sec = jj >> 5, d = jj & 31;
        brr[i] = b_in[sec * 384 + h * 32 + d];
    }
}

// ================= kernel A: QKV projection + window attention =================
// grid: 1024 m-blocks x 6 head-pairs = 6144. block = 512 thr (8 waves).
// BM=128 (8 windows), BN=192 (2 heads x q32|k32|v32), BK=64.
// A comes DIRECTLY from global x (f32 -> bf16 in-reg); only B staged in LDS.
// LDS 48KB: B 2x[192][128B] -> 3 blocks/CU = 6 waves/SIMD.
// attn alias: QKV^T tiles [8 win][2 head][3 sec][32 d][16 t] @0 (48KB exactly)
__global__ __launch_bounds__(512, 6)
void qkv_attn(const float* __restrict__ x, const char* __restrict__ wst,
              const float* __restrict__ brr, char* __restrict__ attst)
{
    __shared__ __align__(16) char smem[49152];

    const int tid  = threadIdx.x;
    const int lane = tid & 63, wid = tid >> 6;         // 8 waves
    const int g = lane >> 4, r16 = lane & 15;
    const int wm = wid >> 1, wn = wid & 1;             // wm 0..3 (M32), wn 0..1 (N96)

    int b = blockIdx.x;
    int L = (b & 7) * 768 + (b >> 3);          // XCD-chunked swizzle (6144 % 8 == 0)
    const int mblk = L / 6, hp = L - mblk * 6;
    const int head = hp * 2 + wn;

    // ---- A row pointers: this lane's 2 token rows (window-remapped) ----
    const float* arow[2];
    #pragma unroll
    for (int mi = 0; mi < 2; ++mi) {
        int T = mblk * 128 + wm * 32 + mi * 16 + r16;
        int win0 = T >> 4, t4 = T & 15;
        int bb0 = win0 >> 8, wh = (win0 >> 4) & 15, ww = win0 & 15;
        arow[mi] = x + ((size_t)bb0 * 4096 +
                        (size_t)((wh * 4 + (t4 >> 2)) * 64 + ww * 4 + (t4 & 3))) * 384
                     + g * 8;
    }

    const char* wst_blk = wst + (size_t)hp * 147456;
    auto stage_B = [&](int s, int buf) {
        char* dst = smem + buf * 24576 + tid * 16;
        const char* src = wst_blk + s * 24576 + tid * 16;
        #pragma unroll
        for (int j = 0; j < 3; ++j) gload16(src + j * 8192, dst + j * 8192);
    };

    f32x4 acc[2][6] = {};
    auto compute = [&](int s, int buf) {
        const char* bbp = smem + buf * 24576;
        #pragma unroll
        for (int c = 0; c < 2; ++c) {
            const int sw = ((c * 4 + g) ^ (r16 & 7)) << 4;
            union U8 { unsigned u[4]; short8 v; } a[2];
            #pragma unroll
            for (int mi = 0; mi < 2; ++mi) {
                const float4* ap = (const float4*)(arow[mi] + s * 64 + c * 32);
                float4 lo = ap[0], hi = ap[1];
                a[mi].u[0] = f2bf(lo.x) | ((unsigned)f2bf(lo.y) << 16);
                a[mi].u[1] = f2bf(lo.z) | ((unsigned)f2bf(lo.w) << 16);
                a[mi].u[2] = f2bf(hi.x) | ((unsigned)f2bf(hi.y) << 16);
                a[mi].u[3] = f2bf(hi.z) | ((unsigned)f2bf(hi.w) << 16);
            }
            #pragma unroll
            for (int ni = 0; ni < 6; ++ni) {
                short8 bf = *(const short8*)(bbp + (wn * 96 + ni * 16 + r16) * 128 + sw);
                acc[0][ni] = MFMA16(a[0].v, bf, acc[0][ni]);
                acc[1][ni] = MFMA16(a[1].v, bf, acc[1][ni]);
            }
        }
    };

    stage_B(0, 0);
    for (int s = 0; s < 6; ++s) {
        __syncthreads();                        // stage_B(s) landed (barrier drains vmcnt)
        if (s < 5) stage_B(s + 1, (s + 1) & 1);
        compute(s, s & 1);
    }
    __syncthreads();  // attn tiles alias B buffers: wait all compute reads done

    // ---- epilogue: acc (+bias) -> Q^T/K^T/V^T tiles [d][t] ----
    float bias[6];
    #pragma unroll
    for (int ni = 0; ni < 6; ++ni) bias[ni] = brr[head * 96 + ni * 16 + r16];

    #pragma unroll
    for (int mi = 0; mi < 2; ++mi) {
        const int win = wm * 2 + mi;
        #pragma unroll
        for (int ni = 0; ni < 6; ++ni) {
            const int sec = ni >> 1;            // 0=Q 1=K 2=V
            const int d = (ni & 1) * 16 + r16;
            float v0 = acc[mi][ni][0] + bias[ni];
            float v1 = acc[mi][ni][1] + bias[ni];
            float v2 = acc[mi][ni][2] + bias[ni];
            float v3 = acc[mi][ni][3] + bias[ni];
            uint2 w;
            w.x = f2bf(v0) | ((unsigned)f2bf(v1) << 16);
            w.y = f2bf(v2) | ((unsigned)f2bf(v3) << 16);
            *(uint2*)(smem + win * 6144 + wn * 3072 + sec * 1024 + d * 32 + g * 8) = w;
        }
    }

    // ---- attention: 2 windows per wave, zero barriers, P stays in registers ----
    const float kC = 0.17677669529663687f * 1.4426950408889634f;  // (1/sqrt32)*log2e
    const f32x4 zero = {0.f, 0.f, 0.f, 0.f};

    #pragma unroll
    for (int i = 0; i < 2; ++i) {
        const int win = wm * 2 + i;
        const char* base = smem + win * 6144 + wn * 3072;

        union U8 { unsigned short e[8]; short8 v; };
        U8 ku, qu;
        #pragma unroll
        for (int j = 0; j < 8; ++j) {
            const int off = (g * 8 + j) * 32 + r16 * 2;   // elem (d, t=r16)
            qu.e[j] = *(const unsigned short*)(base + off);
            ku.e[j] = *(const unsigned short*)(base + 1024 + off);
        }
        f32x4 s = MFMA16(ku.v, qu.v, zero);     // D[key=4g+r][q=r16]

        float m = fmaxf(fmaxf(s[0], s[1]), fmaxf(s[2], s[3]));
        m = fmaxf(m, __shfl_xor(m, 16, 64));
        m = fmaxf(m, __shfl_xor(m, 32, 64));
        float p[4], sum = 0.f;
        #pragma unroll
        for (int r = 0; r < 4; ++r) { p[r] = exp2f((s[r] - m) * kC); sum += p[r]; }
        sum += __shfl_xor(sum, 16, 64);
        sum += __shfl_xor(sum, 32, 64);
        const float inv = 1.f / sum;

        // P as in-register A-fragment under k-perm k=4g+j (upper 4 elems zero);
        // V's B-fragment uses the SAME key permutation.
        U8 pu;
        pu.e[0] = f2bf(p[0] * inv); pu.e[1] = f2bf(p[1] * inv);
        pu.e[2] = f2bf(p[2] * inv); pu.e[3] = f2bf(p[3] * inv);
        pu.e[4] = 0; pu.e[5] = 0; pu.e[6] = 0; pu.e[7] = 0;

        f32x4 o[2];
        #pragma unroll
        for (int ti = 0; ti < 2; ++ti) {
            U8 vu;                               // V[key=4g+j][d=ti*16+r16]
            *(uint2*)&vu.e[0] = *(const uint2*)(base + 2048 + (ti * 16 + r16) * 32 + g * 8);
            vu.e[4] = 0; vu.e[5] = 0; vu.e[6] = 0; vu.e[7] = 0;
            o[ti] = MFMA16(pu.v, vu.v, zero);    // D[q=4g+r][d-col=r16]
        }
        // store att pre-swizzled for out_proj's global_load_lds staging
        #pragma unroll
        for (int ti = 0; ti < 2; ++ti) {
            #pragma unroll
            for (int r = 0; r < 4; ++r) {
                int row7 = win * 16 + g * 4 + r;
                int col = head * 32 + ti * 16 + r16;
                int sst = col >> 6;
                int sl = ((col >> 3) & 7) ^ (row7 & 7);
                *(unsigned short*)(attst + (size_t)mblk * 98304 + sst * 16384
                                   + row7 * 128 + sl * 16 + (col & 7) * 2)
                    = f2bf(o[ti][r]);
            }
        }
    }
}

// ================= kernel B: out projection =================
// grid: 1024 m-blocks x 3 n-blocks = 3072. BM=128, BN=128, BK=64.
__global__ __launch_bounds__(256, 2)
void out_proj(const char* __restrict__ attst, const char* __restrict__ wos,
              const float* __restrict__ b_out, float* __restrict__ out)
{
    __shared__ __align__(16) char smem[65536];  // A 2x16K @0 ; B 2x16K @32768

    const int tid  = threadIdx.x;
    const int lane = tid & 63, wid = tid >> 6;
    const int g = lane >> 4, r16 = lane & 15;
    const int wm = wid >> 1, wn = wid & 1;

    int b = blockIdx.x;
    int L = (b & 7) * 384 + (b >> 3);
    const int mblk = L / 3, nblk = L - mblk * 3;

    auto stage = [&](int s, int buf) {
        const char* asrc = attst + (size_t)mblk * 98304 + s * 16384 + wid * 4096 + lane * 16;
        const char* bsrc = wos   + (size_t)nblk * 98304 + s * 16384 + wid * 4096 + lane * 16;
        char* adst = smem + buf * 16384 + wid * 4096;
        char* bdst = smem + 32768 + buf * 16384 + wid * 4096;
        #pragma unroll
        for (int j = 0; j < 4; ++j) {
            gload16(asrc + j * 1024, adst + j * 1024);
            gload16(bsrc + j * 1024, bdst + j * 1024);
        }
    };

    f32x4 acc[4][4] = {};
    auto compute = [&](int buf) {
        const char* ab = smem + buf * 16384;
        const char* bbp = smem + 32768 + buf * 16384;
        #pragma unroll
        for (int c = 0; c < 2; ++c) {
            const int sw = ((c * 4 + g) ^ (r16 & 7)) << 4;
            short8 a[4], bf[4];
            #pragma unroll
            for (int mi = 0; mi < 4; ++mi)
                a[mi] = *(const short8*)(ab + (wm * 64 + mi * 16 + r16) * 128 + sw);
            #pragma unroll
            for (int ni = 0; ni < 4; ++ni)
                bf[ni] = *(const short8*)(bbp + (wn * 64 + ni * 16 + r16) * 128 + sw);
            #pragma unroll
            for (int mi = 0; mi < 4; ++mi)
                #pragma unroll
                for (int ni = 0; ni < 4; ++ni)
                    acc[mi][ni] = MFMA16(a[mi], bf[ni], acc[mi][ni]);
        }
    };

    stage(0, 0);
    for (int s = 0; s < 6; ++s) {
        __syncthreads();
        if (s < 5) stage(s + 1, (s + 1) & 1);
        compute(s & 1);
    }

    float bias[4];
    #pragma unroll
    for (int ni = 0; ni < 4; ++ni) bias[ni] = b_out[nblk * 128 + wn * 64 + ni * 16 + r16];

    #pragma unroll
    for (int mi = 0; mi < 4; ++mi) {
        #pragma unroll
        for (int r = 0; r < 4; ++r) {
            int T = mblk * 128 + wm * 64 + mi * 16 + g * 4 + r;
            int win = T >> 4, tt = T & 15;
            int bb = win >> 8, wh = (win >> 4) & 15, ww = win & 15;
            size_t o = ((size_t)bb * 4096 + (wh * 4 + (tt >> 2)) * 64 + ww * 4 + (tt & 3)) * 384
                     + nblk * 128 + wn * 64;
            #pragma unroll
            for (int ni = 0; ni < 4; ++ni)
                out[o + ni * 16 + r16] = acc[mi][ni][r] + bias[ni];
        }
    }
}

extern "C" void kernel_launch(void* const* d_in, const int* in_sizes, int n_in,
                              void* d_out, int out_size, void* d_ws, size_t ws_size,
                              hipStream_t stream) {
    const float* x     = (const float*)d_in[0];
    const float* w_in  = (const float*)d_in[1];
    const float* b_in  = (const float*)d_in[2];
    const float* w_out = (const float*)d_in[3];
    const float* b_out = (const float*)d_in[4];
    float* out = (float*)d_out;

    char* ws = (char*)d_ws;
    char*  wst = ws + kWstOff;
    char*  wos = ws + kWosOff;
    float* brr = (float*)(ws + kBrrOff);
    char*  att = ws + kAttOff;

    prep<<<dim3(288), dim3(256), 0, stream>>>(w_in, b_in, w_out, wst, wos, brr);
    qkv_attn<<<dim3(6144), dim3(512), 0, stream>>>(x, wst, brr, att);
    out_proj<<<dim3(3072), dim3(256), 0, stream>>>(att, wos, b_out, out);
}

// Round 8
// 283.246 us; speedup vs baseline: 1.6940x; 1.6940x over previous
//
#include <hip/hip_runtime.h>
#include <hip/hip_bf16.h>

typedef __attribute__((ext_vector_type(8))) short short8;
typedef __attribute__((ext_vector_type(4))) float f32x4;

static __device__ __forceinline__ f32x4 MFMA16(short8 a, short8 b, f32x4 c) {
    return __builtin_amdgcn_mfma_f32_16x16x32_bf16(a, b, c, 0, 0, 0);
}
static __device__ __forceinline__ unsigned short f2bf(float f) {
    union { __hip_bfloat16 h; unsigned short u; } c;
    c.h = __float2bfloat16(f);
    return c.u;
}
static __device__ __forceinline__ void gload16(const void* g, void* l) {
    __builtin_amdgcn_global_load_lds(
        (const __attribute__((address_space(1))) unsigned int*)g,
        (__attribute__((address_space(3))) unsigned int*)l, 16, 0, 0);
}

// ---------------- ws layout ----------------
// wst  : bf16, LDS-order pre-swizzled w_in  [6 hp][6 s][1536 granules x16B] @ 0        (884736)
// wos  : bf16, LDS-order pre-swizzled w_out [3 nb][6 s][1024 granules x16B] @ 884736   (294912)
// brr  : f32  [12][96] head-major bias                                      @ 1179648  (4608)
// attst: bf16, LDS-order pre-swizzled att   [1024 mb][6 s][16384 B]         @ 1184256  (100663296)
constexpr size_t kWstOff = 0;
constexpr size_t kWosOff = 884736;
constexpr size_t kBrrOff = 1179648;
constexpr size_t kAttOff = 1184256;

// ================= kernel 0: prep (convert + reorder + pre-swizzle weights) =====
__global__ void prep(const float* __restrict__ w_in, const float* __restrict__ b_in,
                     const float* __restrict__ w_out,
                     char* __restrict__ wst, char* __restrict__ wos,
                     float* __restrict__ brr)
{
    const int i = blockIdx.x * 256 + threadIdx.x;   // grid covers 73728 exactly
    if (i < 55296) {
        int hp = i / 9216, rem = i % 9216;
        int s = rem / 1536, slot16 = rem % 1536;
        int row = slot16 >> 3, sl = slot16 & 7;
        int c8 = sl ^ (row & 7);
        int hh = row / 96, rr = row % 96;
        int sec = rr >> 5, d = rr & 31;
        int srow = sec * 384 + (hp * 2 + hh) * 32 + d;
        int k0 = s * 64 + c8 * 8;
        const float4* src = (const float4*)(w_in + (size_t)srow * 384 + k0);
        float4 a = src[0], b = src[1];
        uint4 w;
        w.x = f2bf(a.x) | ((unsigned)f2bf(a.y) << 16);
        w.y = f2bf(a.z) | ((unsigned)f2bf(a.w) << 16);
        w.z = f2bf(b.x) | ((unsigned)f2bf(b.y) << 16);
        w.w = f2bf(b.z) | ((unsigned)f2bf(b.w) << 16);
        *(uint4*)(wst + (size_t)i * 16) = w;
    } else {
        int j = i - 55296;                           // [0, 18432)
        int nb = j / 6144, rem = j % 6144;
        int s = rem / 1024, slot16 = rem % 1024;
        int row = slot16 >> 3, sl = slot16 & 7;
        int c8 = sl ^ (row & 7);
        int srow = nb * 128 + row;
        int k0 = s * 64 + c8 * 8;
        const float4* src = (const float4*)(w_out + (size_t)srow * 384 + k0);
        float4 a = src[0], b = src[1];
        uint4 w;
        w.x = f2bf(a.x) | ((unsigned)f2bf(a.y) << 16);
        w.y = f2bf(a.z) | ((unsigned)f2bf(a.w) << 16);
        w.z = f2bf(b.x) | ((unsigned)f2bf(b.y) << 16);
        w.w = f2bf(b.z) | ((unsigned)f2bf(b.w) << 16);
        *(uint4*)(wos + (size_t)j * 16) = w;
    }
    if (i < 1152) {
        int h = i / 96, jj = i % 96;
        int sec = jj >> 5, d = jj & 31;
        brr[i] = b_in[sec * 384 + h * 32 + d];
    }
}

// ================= kernel A: QKV projection + window attention =================
// grid: 1024 m-blocks x 6 head-pairs = 6144. block = 512 thr (8 waves).
// BM=128 (8 windows), BN=192 (2 heads x q32|k32|v32), BK=64.
// LDS 48KB single-buffered: A [128][128B] @0 (16K) ; B [192][128B] @16384 (24K)
//   -> 3 blocks/CU = 6 waves/SIMD (VGPR ~60 <= 85).
// attn alias: QKV^T tiles [8 win][2 head][3 sec][32 d][16 t] @0 (48KB exactly)
__global__ __launch_bounds__(512, 4)
void qkv_attn(const float* __restrict__ x, const char* __restrict__ wst,
              const float* __restrict__ brr, char* __restrict__ attst)
{
    __shared__ __align__(16) char smem[49152];

    const int tid  = threadIdx.x;
    const int lane = tid & 63, wid = tid >> 6;         // 8 waves
    const int g = lane >> 4, r16 = lane & 15;
    const int wm = wid >> 1, wn = wid & 1;             // wm 0..3 (M32), wn 0..1 (N96)

    int b = blockIdx.x;
    int L = (b & 7) * 768 + (b >> 3);          // XCD-chunked swizzle (6144 % 8 == 0)
    const int mblk = L / 6, hp = L - mblk * 6;
    const int head = hp * 2 + wn;

    // ---- A staging map: 512 thr cover 128 rows x 64 f32; 4 float4 per thread ----
    const int arow = tid >> 2, aq = tid & 3;           // quarter-row of 16 f32
    int T0 = mblk * 128 + arow;
    int win0 = T0 >> 4, t4 = T0 & 15;
    int bb0 = win0 >> 8, wh = (win0 >> 4) & 15, ww = win0 & 15;
    const float* xrow = x + ((size_t)bb0 * 4096 +
                             (size_t)((wh * 4 + (t4 >> 2)) * 64 + ww * 4 + (t4 & 3))) * 384
                          + aq * 16;

    float4 af[4];
    auto load_A = [&](int s) {
        const float4* xp = (const float4*)(xrow + s * 64);
        #pragma unroll
        for (int j = 0; j < 4; ++j) af[j] = xp[j];
    };
    auto write_A = [&]() {
        #pragma unroll
        for (int j = 0; j < 2; ++j) {
            uint4 w;
            w.x = f2bf(af[2*j].x)   | ((unsigned)f2bf(af[2*j].y)   << 16);
            w.y = f2bf(af[2*j].z)   | ((unsigned)f2bf(af[2*j].w)   << 16);
            w.z = f2bf(af[2*j+1].x) | ((unsigned)f2bf(af[2*j+1].y) << 16);
            w.w = f2bf(af[2*j+1].z) | ((unsigned)f2bf(af[2*j+1].w) << 16);
            int slot = (aq * 2 + j) ^ (arow & 7);
            *(uint4*)(smem + arow * 128 + slot * 16) = w;
        }
    };
    const char* wst_blk = wst + (size_t)hp * 147456;
    auto stage_B = [&](int s) {
        char* dst = smem + 16384 + tid * 16;
        const char* src = wst_blk + s * 24576 + tid * 16;
        #pragma unroll
        for (int j = 0; j < 3; ++j) gload16(src + j * 8192, dst + j * 8192);
    };

    f32x4 acc[2][6] = {};
    auto compute = [&]() {
        #pragma unroll
        for (int c = 0; c < 2; ++c) {
            const int sw = ((c * 4 + g) ^ (r16 & 7)) << 4;
            short8 a[2], bf[6];
            #pragma unroll
            for (int mi = 0; mi < 2; ++mi)
                a[mi] = *(const short8*)(smem + (wm * 32 + mi * 16 + r16) * 128 + sw);
            #pragma unroll
            for (int ni = 0; ni < 6; ++ni)
                bf[ni] = *(const short8*)(smem + 16384 + (wn * 96 + ni * 16 + r16) * 128 + sw);
            #pragma unroll
            for (int mi = 0; mi < 2; ++mi)
                #pragma unroll
                for (int ni = 0; ni < 6; ++ni)
                    acc[mi][ni] = MFMA16(a[mi], bf[ni], acc[mi][ni]);
        }
    };

    // prologue
    load_A(0);
    stage_B(0);
    write_A();
    // main loop: single-buffered, 2 barriers/step; next A-loads issued under compute
    for (int s = 0; s < 6; ++s) {
        __syncthreads();                       // stage_B(s) + write_A(s) visible
        if (s < 5) load_A(s + 1);              // global->regs: lands during compute
        compute();
        if (s < 5) {
            __syncthreads();                   // all waves done reading A/B(s)
            stage_B(s + 1);
            write_A();
        }
    }
    __syncthreads();  // attn tiles alias staging LDS: wait all compute reads done

    // ---- epilogue: acc (+bias) -> Q^T/K^T/V^T tiles [d][t] ----
    float bias[6];
    #pragma unroll
    for (int ni = 0; ni < 6; ++ni) bias[ni] = brr[head * 96 + ni * 16 + r16];

    #pragma unroll
    for (int mi = 0; mi < 2; ++mi) {
        const int win = wm * 2 + mi;
        #pragma unroll
        for (int ni = 0; ni < 6; ++ni) {
            const int sec = ni >> 1;            // 0=Q 1=K 2=V
            const int d = (ni & 1) * 16 + r16;
            float v0 = acc[mi][ni][0] + bias[ni];
            float v1 = acc[mi][ni][1] + bias[ni];
            float v2 = acc[mi][ni][2] + bias[ni];
            float v3 = acc[mi][ni][3] + bias[ni];
            uint2 w;
            w.x = f2bf(v0) | ((unsigned)f2bf(v1) << 16);
            w.y = f2bf(v2) | ((unsigned)f2bf(v3) << 16);
            *(uint2*)(smem + win * 6144 + wn * 3072 + sec * 1024 + d * 32 + g * 8) = w;
        }
    }

    // ---- attention: 2 windows per wave, zero barriers, P stays in registers ----
    const float kC = 0.17677669529663687f * 1.4426950408889634f;  // (1/sqrt32)*log2e
    const f32x4 zero = {0.f, 0.f, 0.f, 0.f};

    #pragma unroll
    for (int i = 0; i < 2; ++i) {
        const int win = wm * 2 + i;
        const char* base = smem + win * 6144 + wn * 3072;

        union U8 { unsigned short e[8]; short8 v; };
        U8 ku, qu;
        #pragma unroll
        for (int j = 0; j < 8; ++j) {
            const int off = (g * 8 + j) * 32 + r16 * 2;   // elem (d, t=r16)
            qu.e[j] = *(const unsigned short*)(base + off);
            ku.e[j] = *(const unsigned short*)(base + 1024 + off);
        }
        f32x4 s = MFMA16(ku.v, qu.v, zero);     // D[key=4g+r][q=r16]

        float m = fmaxf(fmaxf(s[0], s[1]), fmaxf(s[2], s[3]));
        m = fmaxf(m, __shfl_xor(m, 16, 64));
        m = fmaxf(m, __shfl_xor(m, 32, 64));
        float p[4], sum = 0.f;
        #pragma unroll
        for (int r = 0; r < 4; ++r) { p[r] = exp2f((s[r] - m) * kC); sum += p[r]; }
        sum += __shfl_xor(sum, 16, 64);
        sum += __shfl_xor(sum, 32, 64);
        const float inv = 1.f / sum;

        // P as in-register A-fragment under k-perm k=4g+j (upper 4 elems zero);
        // V's B-fragment uses the SAME key permutation.
        U8 pu;
        pu.e[0] = f2bf(p[0] * inv); pu.e[1] = f2bf(p[1] * inv);
        pu.e[2] = f2bf(p[2] * inv); pu.e[3] = f2bf(p[3] * inv);
        pu.e[4] = 0; pu.e[5] = 0; pu.e[6] = 0; pu.e[7] = 0;

        f32x4 o[2];
        #pragma unroll
        for (int ti = 0; ti < 2; ++ti) {
            U8 vu;                               // V[key=4g+j][d=ti*16+r16]
            *(uint2*)&vu.e[0] = *(const uint2*)(base + 2048 + (ti * 16 + r16) * 32 + g * 8);
            vu.e[4] = 0; vu.e[5] = 0; vu.e[6] = 0; vu.e[7] = 0;
            o[ti] = MFMA16(pu.v, vu.v, zero);    // D[q=4g+r][d-col=r16]
        }
        // store att pre-swizzled for out_proj's global_load_lds staging
        #pragma unroll
        for (int ti = 0; ti < 2; ++ti) {
            #pragma unroll
            for (int r = 0; r < 4; ++r) {
                int row7 = win * 16 + g * 4 + r;
                int col = head * 32 + ti * 16 + r16;
                int sst = col >> 6;
                int sl = ((col >> 3) & 7) ^ (row7 & 7);
                *(unsigned short*)(attst + (size_t)mblk * 98304 + sst * 16384
                                   + row7 * 128 + sl * 16 + (col & 7) * 2)
                    = f2bf(o[ti][r]);
            }
        }
    }
}

// ================= kernel B: out projection =================
// grid: 1024 m-blocks x 3 n-blocks = 3072. BM=128, BN=128, BK=64.
__global__ __launch_bounds__(256, 2)
void out_proj(const char* __restrict__ attst, const char* __restrict__ wos,
              const float* __restrict__ b_out, float* __restrict__ out)
{
    __shared__ __align__(16) char smem[65536];  // A 2x16K @0 ; B 2x16K @32768

    const int tid  = threadIdx.x;
    const int lane = tid & 63, wid = tid >> 6;
    const int g = lane >> 4, r16 = lane & 15;
    const int wm = wid >> 1, wn = wid & 1;

    int b = blockIdx.x;
    int L = (b & 7) * 384 + (b >> 3);
    const int mblk = L / 3, nblk = L - mblk * 3;

    auto stage = [&](int s, int buf) {
        const char* asrc = attst + (size_t)mblk * 98304 + s * 16384 + wid * 4096 + lane * 16;
        const char* bsrc = wos   + (size_t)nblk * 98304 + s * 16384 + wid * 4096 + lane * 16;
        char* adst = smem + buf * 16384 + wid * 4096;
        char* bdst = smem + 32768 + buf * 16384 + wid * 4096;
        #pragma unroll
        for (int j = 0; j < 4; ++j) {
            gload16(asrc + j * 1024, adst + j * 1024);
            gload16(bsrc + j * 1024, bdst + j * 1024);
        }
    };

    f32x4 acc[4][4] = {};
    auto compute = [&](int buf) {
        const char* ab = smem + buf * 16384;
        const char* bbp = smem + 32768 + buf * 16384;
        #pragma unroll
        for (int c = 0; c < 2; ++c) {
            const int sw = ((c * 4 + g) ^ (r16 & 7)) << 4;
            short8 a[4], bf[4];
            #pragma unroll
            for (int mi = 0; mi < 4; ++mi)
                a[mi] = *(const short8*)(ab + (wm * 64 + mi * 16 + r16) * 128 + sw);
            #pragma unroll
            for (int ni = 0; ni < 4; ++ni)
                bf[ni] = *(const short8*)(bbp + (wn * 64 + ni * 16 + r16) * 128 + sw);
            #pragma unroll
            for (int mi = 0; mi < 4; ++mi)
                #pragma unroll
                for (int ni = 0; ni < 4; ++ni)
                    acc[mi][ni] = MFMA16(a[mi], bf[ni], acc[mi][ni]);
        }
    };

    stage(0, 0);
    for (int s = 0; s < 6; ++s) {
        __syncthreads();
        if (s < 5) stage(s + 1, (s + 1) & 1);
        compute(s & 1);
    }

    float bias[4];
    #pragma unroll
    for (int ni = 0; ni < 4; ++ni) bias[ni] = b_out[nblk * 128 + wn * 64 + ni * 16 + r16];

    #pragma unroll
    for (int mi = 0; mi < 4; ++mi) {
        #pragma unroll
        for (int r = 0; r < 4; ++r) {
            int T = mblk * 128 + wm * 64 + mi * 16 + g * 4 + r;
            int win = T >> 4, tt = T & 15;
            int bb = win >> 8, wh = (win >> 4) & 15, ww = win & 15;
            size_t o = ((size_t)bb * 4096 + (wh * 4 + (tt >> 2)) * 64 + ww * 4 + (tt & 3)) * 384
                     + nblk * 128 + wn * 64;
            #pragma unroll
            for (int ni = 0; ni < 4; ++ni)
                out[o + ni * 16 + r16] = acc[mi][ni][r] + bias[ni];
        }
    }
}

extern "C" void kernel_launch(void* const* d_in, const int* in_sizes, int n_in,
                              void* d_out, int out_size, void* d_ws, size_t ws_size,
                              hipStream_t stream) {
    const float* x     = (const float*)d_in[0];
    const float* w_in  = (const float*)d_in[1];
    const float* b_in  = (const float*)d_in[2];
    const float* w_out = (const float*)d_in[3];
    const float* b_out = (const float*)d_in[4];
    float* out = (float*)d_out;

    char* ws = (char*)d_ws;
    char*  wst = ws + kWstOff;
    char*  wos = ws + kWosOff;
    float* brr = (float*)(ws + kBrrOff);
    char*  att = ws + kAttOff;

    prep<<<dim3(288), dim3(256), 0, stream>>>(w_in, b_in, w_out, wst, wos, brr);
    qkv_attn<<<dim3(6144), dim3(512), 0, stream>>>(x, wst, brr, att);
    out_proj<<<dim3(3072), dim3(256), 0, stream>>>(att, wos, b_out, out);
}